// Round 5
// baseline (533.660 us; speedup 1.0000x reference)
//
#include <hip/hip_runtime.h>
#include <hip/hip_bf16.h>

#define NBASIS 10
#define CDIM 16
#define DKDIM 8
#define JDIM 16

typedef float v4f __attribute__((ext_vector_type(4)));

#if __has_builtin(__builtin_elementwise_fma)
#define VFMA4(a, b, c) __builtin_elementwise_fma(a, b, c)
#else
__device__ __forceinline__ v4f VFMA4(v4f a, v4f b, v4f c) {
    v4f r; r.x = fmaf(a.x, b.x, c.x); r.y = fmaf(a.y, b.y, c.y);
    r.z = fmaf(a.z, b.z, c.z); r.w = fmaf(a.w, b.w, c.w); return r;
}
#endif

// adaptive load: f32 flag (wave-uniform) selects fp32 or bf16 interpretation
__device__ __forceinline__ float ldf(const void* p, int i, int f32) {
    if (f32) return ((const float*)p)[i];
    return __bfloat162float(((const __hip_bfloat16*)p)[i]);
}

// per-wave input-dtype detect (see round-2 notes): fp32 data read as bf16
// shows implausible magnitudes in ~half the ushorts; bf16 N(0,1) shows none.
__device__ __forceinline__ int detect_f32(const void* x) {
    unsigned short b = ((const unsigned short*)x)[threadIdx.x & 63];
    float v = __uint_as_float(((unsigned int)b) << 16);
    bool bad = !(fabsf(v) < 1000.0f) || (v != 0.0f && fabsf(v) < 1e-15f);
    unsigned long long m = __ballot(bad);
    return (__popcll(m) >= 8) ? 1 : 0;
}

__device__ __forceinline__ const float* uniform_ptr(const float* p) {
    uint64_t v = (uint64_t)p;
    uint32_t lo = __builtin_amdgcn_readfirstlane((uint32_t)v);
    uint32_t hi = __builtin_amdgcn_readfirstlane((uint32_t)(v >> 32));
    return (const float*)(((uint64_t)hi << 32) | lo);
}

// ---------------- prep: weights->fp32, q = x@Wq, zero z/outacc/zerobuf ------
__global__ __launch_bounds__(256) void prep_kernel(
    const void* __restrict__ x, const void* __restrict__ Wq,
    const void* __restrict__ Wk1, const void* __restrict__ Wk2,
    const void* __restrict__ Wv1, const void* __restrict__ Wv2,
    float* __restrict__ w2k, float* __restrict__ w2v,
    float* __restrict__ w1k, float* __restrict__ w1v,
    float* __restrict__ qbuf, float* __restrict__ zbuf,
    float* __restrict__ outacc, int* __restrict__ zerobuf, int N)
{
    const int f32 = detect_f32(x);
    int i = blockIdx.x * 256 + threadIdx.x;
    if (i < 32768) { w2k[i] = ldf(Wk2, i, f32); w2v[i] = ldf(Wv2, i, f32); }
    if (i < 160)   { w1k[i] = ldf(Wk1, i, f32); w1v[i] = ldf(Wv1, i, f32); }
    if (i < 64)    zerobuf[i] = 0;
    if (i < N)     zbuf[i] = 0.0f;
    if (i < N * 8) {
        outacc[i] = 0.0f;
        int n = i >> 3, o = i & 7;
        float acc = 0.0f;
        #pragma unroll
        for (int c = 0; c < CDIM; ++c)
            acc = fmaf(ldf(x, n * CDIM + c, f32), ldf(Wq, c * DKDIM + o, f32), acc);
        qbuf[i] = acc;
    }
}

// ---------------- heavy per-edge kernel -------------------------------------
// block = 512 threads = 8 waves handling the SAME 64 edges:
//   wave w: net = w&1 (0=k,1=v), m-quarter = (w>>1)*4
// W2 is streamed via the VMEM path (pointer tainted with an opaque per-lane
// zero) -> global_load_dwordx4, lane-uniform addresses coalesce+broadcast.
// Epilogue folds the softmax: out += sqrt(ev)*v here; finalize divides by
// sqrt(z) (algebraically identical to sqrt(ev/z)*v).
__global__ __launch_bounds__(512) void edge_kernel(
    const void* __restrict__ pos, const void* __restrict__ x,
    const int* __restrict__ esrc, const int* __restrict__ edst,
    const float* __restrict__ w2k, const float* __restrict__ w2v,
    const float* __restrict__ w1k, const float* __restrict__ w1v,
    const float* __restrict__ qbuf, const int* __restrict__ zerobuf,
    float* __restrict__ zbuf, float* __restrict__ outacc, int E)
{
    __shared__ float xs_lds[64][17];     // block's 64 xs rows (+1 pad)
    __shared__ float part[6][64][9];     // partials from waves 2..7 (+1 pad)
    __shared__ float evs[64];            // ev handoff k-wave -> v-wave

    const int f32  = detect_f32(x);
    const int tid  = threadIdx.x;
    const int lane = tid & 63;
    const int w    = tid >> 6;
    const int net  = w & 1;
    int mq = (w >> 1) * 4;
    mq = __builtin_amdgcn_readfirstlane(mq);
    const float* w1 = uniform_ptr(net ? w1v : w1k);
    // opaque per-lane zero: value is 0 at runtime but the compiler cannot
    // prove it -> W2 accesses become VMEM (vector) loads, not s_load.
    const int vzero = zerobuf[lane];
    const float* w2l = uniform_ptr(net ? w2v : w2k) + vzero;

    const int e0 = blockIdx.x * 64;
    const int e  = e0 + lane;
    const bool act = e < E;
    const int eidx = act ? e : 0;

    // cooperative xs stage: 64 edges x 16 channels, 2 values/thread
    #pragma unroll
    for (int idx = tid; idx < 1024; idx += 512) {
        int row = idx >> 4, c = idx & 15;
        int ee = e0 + row; ee = (ee < E) ? ee : (E - 1);
        int sr = esrc[ee];
        xs_lds[row][c] = ldf(x, sr * CDIM + c, f32);
    }

    const int s = esrc[eidx], d = edst[eidx];

    float vx = ldf(pos, s * 3 + 0, f32) - ldf(pos, d * 3 + 0, f32);
    float vy = ldf(pos, s * 3 + 1, f32) - ldf(pos, d * 3 + 1, f32);
    float vz = ldf(pos, s * 3 + 2, f32) - ldf(pos, d * 3 + 2, f32);
    float r2 = vx * vx + vy * vy + vz * vz;
    float r  = sqrtf(r2 + 1e-18f);          // ref: emb/cutoff radius has +eps
    float rsh = sqrtf(r2);                  // ref: SH radius has no eps
    float inv = 1.0f / fmaxf(rsh, 1e-9f);
    float ux = vx * inv, uy = vy * inv, uz = vz * inv;

    float sh[16];
    {
        const float s3   = 1.7320508075688772f;
        const float s5   = 2.23606797749979f;
        const float s15  = 3.872983346207417f;
        const float c358 = 2.091650066335189f;   // sqrt(35/8)
        const float c218 = 1.6201851746019651f;  // sqrt(21/8)
        const float s105 = 10.246950765959598f;  // sqrt(105)
        const float s7h  = 1.3228756555322954f;  // sqrt(7)/2
        float xx = ux * ux, yy = uy * uy, zz = uz * uz;
        sh[0] = 1.0f;
        sh[1] = s3 * ux; sh[2] = s3 * uy; sh[3] = s3 * uz;
        sh[4] = s15 * ux * uy;
        sh[5] = s15 * uy * uz;
        sh[6] = 0.5f * s5 * (3.0f * zz - 1.0f);
        sh[7] = s15 * ux * uz;
        sh[8] = 0.5f * s15 * (xx - yy);
        sh[9] = c358 * uy * (3.0f * xx - yy);
        sh[10] = s105 * ux * uy * uz;
        sh[11] = c218 * uy * (5.0f * zz - 1.0f);
        sh[12] = s7h * uz * (5.0f * zz - 3.0f);
        sh[13] = c218 * ux * (5.0f * zz - 1.0f);
        sh[14] = 0.5f * s105 * uz * (xx - yy);
        sh[15] = c358 * ux * (xx - 3.0f * yy);
    }

    // radial embedding -> hidden activations for this wave's 4 m values
    float hm[4];
    {
        float emb[NBASIS];
        const float step = 3.5f / 11.0f;
        const float istep = 11.0f / 3.5f;
        const float coef = (float)(1.14136 * 7.38905609893065 * 3.1622776601683795);
        #pragma unroll
        for (int i = 0; i < NBASIS; ++i) {
            float u = (r - step * (float)(i + 1)) * istep;
            float uu = u * u;
            emb[i] = (uu < 1.0f) ? coef * expf(-1.0f / (1.0f - uu)) : 0.0f;
        }
        const float inv_s10 = 0.31622776601683794f; // 1/sqrt(10)
        #pragma unroll
        for (int m = 0; m < 4; ++m) {
            float pre = 0.0f;
            #pragma unroll
            for (int nb = 0; nb < NBASIS; ++nb)
                pre = fmaf(emb[nb], w1[nb * 16 + mq + m], pre);
            pre *= inv_s10;
            hm[m] = pre / (1.0f + expf(-pre));   // silu
        }
    }
    float tcut = 10.0f * (1.0f - r * (1.0f / 3.5f));
    float cutoff = (tcut > 0.0f) ? expf(-1.0f / tcut) : 0.0f;

    __syncthreads();   // xs_lds ready

    v4f acc4[2];
    acc4[0] = (v4f){0.f, 0.f, 0.f, 0.f};
    acc4[1] = (v4f){0.f, 0.f, 0.f, 0.f};

    #pragma unroll 1
    for (int m = 0; m < 4; ++m) {
        const v4f* wm4 = (const v4f*)(w2l + (mq + m) * 2048);
        float h = hm[m];
        #pragma unroll 1
        for (int c = 0; c < CDIM; ++c) {
            float a = h * xs_lds[lane][c];
            const v4f* wc4 = wm4 + c * 32;
            #pragma unroll
            for (int j = 0; j < JDIM; ++j) {
                float b = a * sh[j];
                v4f bv = {b, b, b, b};
                acc4[0] = VFMA4(bv, wc4[j * 2 + 0], acc4[0]);
                acc4[1] = VFMA4(bv, wc4[j * 2 + 1], acc4[1]);
            }
        }
    }

    float acc[8];
    const float scale = 1.0f / 64.0f;  // 1/sqrt(16) fcnet * 1/sqrt(256) norm
    #pragma unroll
    for (int p = 0; p < 4; ++p) {
        acc[p]     = acc4[0][p] * scale;
        acc[4 + p] = acc4[1][p] * scale;
    }

    if (w >= 2) {
        #pragma unroll
        for (int o = 0; o < 8; ++o) part[w - 2][lane][o] = acc[o];
    }
    __syncthreads();
    if (w < 2) {
        // net-0 partials in slots {0,2,4}; net-1 in {1,3,5}
        #pragma unroll
        for (int t = 0; t < 3; ++t) {
            #pragma unroll
            for (int o = 0; o < 8; ++o) acc[o] += part[2 * t + net][lane][o];
        }
    }
    if (w == 0) {               // k-net: logit -> ev; share with v-wave
        float ev = 0.0f;
        if (act) {
            float logit = 0.0f;
            #pragma unroll
            for (int o = 0; o < 8; ++o)
                logit = fmaf(qbuf[(size_t)d * 8 + o], acc[o], logit);
            logit *= 0.35355339059327373f;  // 1/sqrt(8)
            ev = cutoff * expf(logit);      // unstabilized, matches ref
            atomicAdd(&zbuf[d], ev);
        }
        evs[lane] = ev;
    }
    __syncthreads();
    if (w == 1 && act) {        // v-net: out += sqrt(ev) * v  (z folded later)
        float wsq = sqrtf(evs[lane]);
        #pragma unroll
        for (int o = 0; o < 8; ++o)
            atomicAdd(&outacc[(size_t)d * 8 + o], wsq * acc[o]);
    }
}

// ---------------- finalize: out = outacc / sqrt(z), dtype-adaptive ----------
__global__ __launch_bounds__(256) void finalize_kernel(
    const float* __restrict__ outacc, const float* __restrict__ zbuf,
    void* __restrict__ out, const void* __restrict__ x, int n)
{
    const int f32 = detect_f32(x);
    int i = blockIdx.x * 256 + threadIdx.x;
    if (i < n) {
        float z = zbuf[i >> 3];
        z = (z == 0.0f) ? 1.0f : z;
        float val = outacc[i] / sqrtf(z);
        if (f32) ((float*)out)[i] = val;
        else ((__hip_bfloat16*)out)[i] = __float2bfloat16(val);
    }
}

extern "C" void kernel_launch(void* const* d_in, const int* in_sizes, int n_in,
                              void* d_out, int out_size, void* d_ws, size_t ws_size,
                              hipStream_t stream)
{
    const void* pos = d_in[0];
    const void* x   = d_in[1];
    const void* Wq  = d_in[2];
    const void* Wk1 = d_in[3];
    const void* Wk2 = d_in[4];
    const void* Wv1 = d_in[5];
    const void* Wv2 = d_in[6];
    const int* esrc = (const int*)d_in[7];
    const int* edst = (const int*)d_in[8];
    const int N = in_sizes[1] / CDIM;
    const int E = in_sizes[7];

    float* ws = (float*)d_ws;
    float* w2k     = ws;
    float* w2v     = w2k + 32768;
    float* w1k     = w2v + 32768;
    float* w1v     = w1k + 160;
    float* qbuf    = w1v + 160;
    float* zbuf    = qbuf + (size_t)N * 8;
    float* outacc  = zbuf + N;
    int*   zerobuf = (int*)(outacc + (size_t)N * 8);

    int prep_threads = N * 8 > 32768 ? N * 8 : 32768;
    int prep_blocks = (prep_threads + 255) / 256;
    prep_kernel<<<prep_blocks, 256, 0, stream>>>(x, Wq, Wk1, Wk2, Wv1, Wv2,
                                                 w2k, w2v, w1k, w1v,
                                                 qbuf, zbuf, outacc, zerobuf, N);

    int edge_blocks = (E + 63) / 64;
    edge_kernel<<<edge_blocks, 512, 0, stream>>>(pos, x, esrc, edst,
                                                 w2k, w2v, w1k, w1v, qbuf,
                                                 zerobuf, zbuf, outacc, E);

    finalize_kernel<<<(N * 8 + 255) / 256, 256, 0, stream>>>(
        outacc, zbuf, d_out, x, N * 8);
}

// Round 6
// 175.391 us; speedup vs baseline: 3.0427x; 3.0427x over previous
//
#include <hip/hip_runtime.h>
#include <hip/hip_bf16.h>

#define NBASIS 10
#define CDIM 16
#define DKDIM 8
#define JDIM 16

typedef float v2f __attribute__((ext_vector_type(2)));

#if __has_builtin(__builtin_elementwise_fma)
#define VFMA2(a, b, c) __builtin_elementwise_fma(a, b, c)
#else
__device__ __forceinline__ v2f VFMA2(v2f a, v2f b, v2f c) {
    v2f r; r.x = fmaf(a.x, b.x, c.x); r.y = fmaf(a.y, b.y, c.y); return r;
}
#endif

// adaptive load: f32 flag (wave-uniform) selects fp32 or bf16 interpretation
__device__ __forceinline__ float ldf(const void* p, int i, int f32) {
    if (f32) return ((const float*)p)[i];
    return __bfloat162float(((const __hip_bfloat16*)p)[i]);
}

// per-wave input-dtype detect (round-2 notes): fp32 data read as bf16 shows
// implausible magnitudes in ~half the ushorts; bf16 N(0,1) shows none.
__device__ __forceinline__ int detect_f32(const void* x) {
    unsigned short b = ((const unsigned short*)x)[threadIdx.x & 63];
    float v = __uint_as_float(((unsigned int)b) << 16);
    bool bad = !(fabsf(v) < 1000.0f) || (v != 0.0f && fabsf(v) < 1e-15f);
    unsigned long long m = __ballot(bad);
    return (__popcll(m) >= 8) ? 1 : 0;
}

__device__ __forceinline__ const float* uniform_ptr(const float* p) {
    uint64_t v = (uint64_t)p;
    uint32_t lo = __builtin_amdgcn_readfirstlane((uint32_t)v);
    uint32_t hi = __builtin_amdgcn_readfirstlane((uint32_t)(v >> 32));
    return (const float*)(((uint64_t)hi << 32) | lo);
}

// ---------------- prep: weights->fp32, q = x@Wq, zero z/outacc --------------
__global__ __launch_bounds__(256) void prep_kernel(
    const void* __restrict__ x, const void* __restrict__ Wq,
    const void* __restrict__ Wk1, const void* __restrict__ Wk2,
    const void* __restrict__ Wv1, const void* __restrict__ Wv2,
    float* __restrict__ w2k, float* __restrict__ w2v,
    float* __restrict__ w1k, float* __restrict__ w1v,
    float* __restrict__ qbuf, float* __restrict__ zbuf,
    float* __restrict__ outacc, int N)
{
    const int f32 = detect_f32(x);
    int i = blockIdx.x * 256 + threadIdx.x;
    if (i < 32768) { w2k[i] = ldf(Wk2, i, f32); w2v[i] = ldf(Wv2, i, f32); }
    if (i < 160)   { w1k[i] = ldf(Wk1, i, f32); w1v[i] = ldf(Wv1, i, f32); }
    if (i < N)     zbuf[i] = 0.0f;
    if (i < N * 8) {
        outacc[i] = 0.0f;
        int n = i >> 3, o = i & 7;
        float acc = 0.0f;
        #pragma unroll
        for (int c = 0; c < CDIM; ++c)
            acc = fmaf(ldf(x, n * CDIM + c, f32), ldf(Wq, c * DKDIM + o, f32), acc);
        qbuf[i] = acc;
    }
}

// ---------------- heavy per-edge kernel -------------------------------------
// block = 512 threads = 8 waves handling the SAME 128 edges (2 per lane):
//   wave w: net = w&1 (0=k,1=v), m-quarter = (w>>1)*4
// W2 streams through the SCALAR path (wave-uniform s_load) — each 16B W2
// value now feeds FMAs for TWO edges, halving scalar-supply pressure.
// Softmax folded: out += sqrt(ev)*v here; finalize divides by sqrt(z).
__global__ __launch_bounds__(512) void edge_kernel(
    const void* __restrict__ pos, const void* __restrict__ x,
    const int* __restrict__ esrc, const int* __restrict__ edst,
    const float* __restrict__ w2k, const float* __restrict__ w2v,
    const float* __restrict__ w1k, const float* __restrict__ w1v,
    const float* __restrict__ qbuf,
    float* __restrict__ zbuf, float* __restrict__ outacc, int E)
{
    __shared__ float xs_lds[128][17];    // block's 128 xs rows (+1 pad)
    __shared__ float part[6][128][9];    // partials from waves 2..7 (+1 pad)
    __shared__ float evs[128];           // ev handoff k-wave -> v-wave

    const int f32  = detect_f32(x);
    const int tid  = threadIdx.x;
    const int lane = tid & 63;
    const int w    = tid >> 6;
    const int net  = w & 1;
    int mq = (w >> 1) * 4;
    mq = __builtin_amdgcn_readfirstlane(mq);
    const float* w1 = uniform_ptr(net ? w1v : w1k);
    const float* w2 = uniform_ptr(net ? w2v : w2k);

    const int e0 = blockIdx.x * 128;

    // cooperative xs stage: 128 edges x 16 channels, 4 values/thread
    #pragma unroll
    for (int idx = tid; idx < 2048; idx += 512) {
        int row = idx >> 4, c = idx & 15;
        int ee = e0 + row; ee = (ee < E) ? ee : (E - 1);
        int sr = esrc[ee];
        xs_lds[row][c] = ldf(x, sr * CDIM + c, f32);
    }

    // per-edge setup for this lane's two edges (t=0: lane, t=1: 64+lane)
    int   d2[2];  bool act2[2];
    float sh2[2][16], hm2[2][4], cut2[2];
    #pragma unroll
    for (int t = 0; t < 2; ++t) {
        const int e = e0 + t * 64 + lane;
        const bool act = e < E;
        act2[t] = act;
        const int eidx = act ? e : 0;
        const int s = esrc[eidx], d = edst[eidx];
        d2[t] = d;

        float vx = ldf(pos, s * 3 + 0, f32) - ldf(pos, d * 3 + 0, f32);
        float vy = ldf(pos, s * 3 + 1, f32) - ldf(pos, d * 3 + 1, f32);
        float vz = ldf(pos, s * 3 + 2, f32) - ldf(pos, d * 3 + 2, f32);
        float r2 = vx * vx + vy * vy + vz * vz;
        float r  = sqrtf(r2 + 1e-18f);      // ref: emb/cutoff radius has +eps
        float rsh = sqrtf(r2);              // ref: SH radius has no eps
        float inv = 1.0f / fmaxf(rsh, 1e-9f);
        float ux = vx * inv, uy = vy * inv, uz = vz * inv;

        {
            const float s3   = 1.7320508075688772f;
            const float s5   = 2.23606797749979f;
            const float s15  = 3.872983346207417f;
            const float c358 = 2.091650066335189f;   // sqrt(35/8)
            const float c218 = 1.6201851746019651f;  // sqrt(21/8)
            const float s105 = 10.246950765959598f;  // sqrt(105)
            const float s7h  = 1.3228756555322954f;  // sqrt(7)/2
            float xx = ux * ux, yy = uy * uy, zz = uz * uz;
            sh2[t][0] = 1.0f;
            sh2[t][1] = s3 * ux; sh2[t][2] = s3 * uy; sh2[t][3] = s3 * uz;
            sh2[t][4] = s15 * ux * uy;
            sh2[t][5] = s15 * uy * uz;
            sh2[t][6] = 0.5f * s5 * (3.0f * zz - 1.0f);
            sh2[t][7] = s15 * ux * uz;
            sh2[t][8] = 0.5f * s15 * (xx - yy);
            sh2[t][9] = c358 * uy * (3.0f * xx - yy);
            sh2[t][10] = s105 * ux * uy * uz;
            sh2[t][11] = c218 * uy * (5.0f * zz - 1.0f);
            sh2[t][12] = s7h * uz * (5.0f * zz - 3.0f);
            sh2[t][13] = c218 * ux * (5.0f * zz - 1.0f);
            sh2[t][14] = 0.5f * s105 * uz * (xx - yy);
            sh2[t][15] = c358 * ux * (xx - 3.0f * yy);
        }
        {
            float emb[NBASIS];
            const float step = 3.5f / 11.0f;
            const float istep = 11.0f / 3.5f;
            const float coef = (float)(1.14136 * 7.38905609893065 * 3.1622776601683795);
            #pragma unroll
            for (int i = 0; i < NBASIS; ++i) {
                float u = (r - step * (float)(i + 1)) * istep;
                float uu = u * u;
                emb[i] = (uu < 1.0f) ? coef * expf(-1.0f / (1.0f - uu)) : 0.0f;
            }
            const float inv_s10 = 0.31622776601683794f; // 1/sqrt(10)
            #pragma unroll
            for (int m = 0; m < 4; ++m) {
                float pre = 0.0f;
                #pragma unroll
                for (int nb = 0; nb < NBASIS; ++nb)
                    pre = fmaf(emb[nb], w1[nb * 16 + mq + m], pre);
                pre *= inv_s10;
                hm2[t][m] = pre / (1.0f + expf(-pre));   // silu
            }
        }
        float tcut = 10.0f * (1.0f - r * (1.0f / 3.5f));
        cut2[t] = (tcut > 0.0f) ? expf(-1.0f / tcut) : 0.0f;
    }

    __syncthreads();   // xs_lds ready

    v2f accA[4], accB[4];
    #pragma unroll
    for (int p = 0; p < 4; ++p) {
        accA[p] = (v2f){0.f, 0.f};
        accB[p] = (v2f){0.f, 0.f};
    }

    #pragma unroll 1
    for (int m = 0; m < 4; ++m) {
        const float* wm = w2 + (mq + m) * 2048;
        const float hA = hm2[0][m], hB = hm2[1][m];
        #pragma unroll 1
        for (int c = 0; c < CDIM; ++c) {
            float aA = hA * xs_lds[lane][c];
            float aB = hB * xs_lds[64 + lane][c];
            const v2f* wc2 = (const v2f*)(wm + c * 128);
            #pragma unroll
            for (int j = 0; j < JDIM; ++j) {
                float bA = aA * sh2[0][j];
                float bB = aB * sh2[1][j];
                v2f bvA = {bA, bA}, bvB = {bB, bB};
                #pragma unroll
                for (int p = 0; p < 4; ++p) {
                    v2f wv = wc2[j * 4 + p];
                    accA[p] = VFMA2(bvA, wv, accA[p]);
                    accB[p] = VFMA2(bvB, wv, accB[p]);
                }
            }
        }
    }

    float acc[2][8];
    const float scale = 1.0f / 64.0f;  // 1/sqrt(16) fcnet * 1/sqrt(256) norm
    #pragma unroll
    for (int p = 0; p < 4; ++p) {
        acc[0][2 * p]     = accA[p].x * scale;
        acc[0][2 * p + 1] = accA[p].y * scale;
        acc[1][2 * p]     = accB[p].x * scale;
        acc[1][2 * p + 1] = accB[p].y * scale;
    }

    if (w >= 2) {
        #pragma unroll
        for (int t = 0; t < 2; ++t)
            #pragma unroll
            for (int o = 0; o < 8; ++o)
                part[w - 2][t * 64 + lane][o] = acc[t][o];
    }
    __syncthreads();
    if (w < 2) {
        // net-0 partials in slots {0,2,4}; net-1 in {1,3,5}
        #pragma unroll
        for (int slot = 0; slot < 3; ++slot)
            #pragma unroll
            for (int t = 0; t < 2; ++t)
                #pragma unroll
                for (int o = 0; o < 8; ++o)
                    acc[t][o] += part[2 * slot + net][t * 64 + lane][o];
    }
    if (w == 0) {               // k-net: logit -> ev; share with v-wave
        #pragma unroll
        for (int t = 0; t < 2; ++t) {
            float ev = 0.0f;
            if (act2[t]) {
                const int d = d2[t];
                float logit = 0.0f;
                #pragma unroll
                for (int o = 0; o < 8; ++o)
                    logit = fmaf(qbuf[(size_t)d * 8 + o], acc[t][o], logit);
                logit *= 0.35355339059327373f;  // 1/sqrt(8)
                ev = cut2[t] * expf(logit);     // unstabilized, matches ref
                atomicAdd(&zbuf[d], ev);
            }
            evs[t * 64 + lane] = ev;
        }
    }
    __syncthreads();
    if (w == 1) {               // v-net: out += sqrt(ev) * v  (z folded later)
        #pragma unroll
        for (int t = 0; t < 2; ++t) {
            if (act2[t]) {
                float wsq = sqrtf(evs[t * 64 + lane]);
                const int d = d2[t];
                #pragma unroll
                for (int o = 0; o < 8; ++o)
                    atomicAdd(&outacc[(size_t)d * 8 + o], wsq * acc[t][o]);
            }
        }
    }
}

// ---------------- finalize: out = outacc / sqrt(z), dtype-adaptive ----------
__global__ __launch_bounds__(256) void finalize_kernel(
    const float* __restrict__ outacc, const float* __restrict__ zbuf,
    void* __restrict__ out, const void* __restrict__ x, int n)
{
    const int f32 = detect_f32(x);
    int i = blockIdx.x * 256 + threadIdx.x;
    if (i < n) {
        float z = zbuf[i >> 3];
        z = (z == 0.0f) ? 1.0f : z;
        float val = outacc[i] / sqrtf(z);
        if (f32) ((float*)out)[i] = val;
        else ((__hip_bfloat16*)out)[i] = __float2bfloat16(val);
    }
}

extern "C" void kernel_launch(void* const* d_in, const int* in_sizes, int n_in,
                              void* d_out, int out_size, void* d_ws, size_t ws_size,
                              hipStream_t stream)
{
    const void* pos = d_in[0];
    const void* x   = d_in[1];
    const void* Wq  = d_in[2];
    const void* Wk1 = d_in[3];
    const void* Wk2 = d_in[4];
    const void* Wv1 = d_in[5];
    const void* Wv2 = d_in[6];
    const int* esrc = (const int*)d_in[7];
    const int* edst = (const int*)d_in[8];
    const int N = in_sizes[1] / CDIM;
    const int E = in_sizes[7];

    float* ws = (float*)d_ws;
    float* w2k     = ws;
    float* w2v     = w2k + 32768;
    float* w1k     = w2v + 32768;
    float* w1v     = w1k + 160;
    float* qbuf    = w1v + 160;
    float* zbuf    = qbuf + (size_t)N * 8;
    float* outacc  = zbuf + N;

    int prep_threads = N * 8 > 32768 ? N * 8 : 32768;
    int prep_blocks = (prep_threads + 255) / 256;
    prep_kernel<<<prep_blocks, 256, 0, stream>>>(x, Wq, Wk1, Wk2, Wv1, Wv2,
                                                 w2k, w2v, w1k, w1v,
                                                 qbuf, zbuf, outacc, N);

    int edge_blocks = (E + 127) / 128;
    edge_kernel<<<edge_blocks, 512, 0, stream>>>(pos, x, esrc, edst,
                                                 w2k, w2v, w1k, w1v, qbuf,
                                                 zbuf, outacc, E);

    finalize_kernel<<<(N * 8 + 255) / 256, 256, 0, stream>>>(
        outacc, zbuf, d_out, x, N * 8);
}

// Round 7
// 128.700 us; speedup vs baseline: 4.1465x; 1.3628x over previous
//
#include <hip/hip_runtime.h>
#include <hip/hip_bf16.h>

#define NBASIS 10
#define CDIM 16
#define DKDIM 8
#define JDIM 16
#define ST 257   // T row stride in floats (odd mod 32 -> conflict-free epilogue reads)

typedef _Float16 half8 __attribute__((ext_vector_type(8)));
typedef float floatx4 __attribute__((ext_vector_type(4)));

// adaptive load: f32 flag (wave-uniform) selects fp32 or bf16 interpretation
__device__ __forceinline__ float ldf(const void* p, int i, int f32) {
    if (f32) return ((const float*)p)[i];
    return __bfloat162float(((const __hip_bfloat16*)p)[i]);
}

// per-wave input-dtype detect (round-2 notes): fp32 data read as bf16 shows
// implausible magnitudes in ~half the ushorts; bf16 N(0,1) shows none.
__device__ __forceinline__ int detect_f32(const void* x) {
    unsigned short b = ((const unsigned short*)x)[threadIdx.x & 63];
    float v = __uint_as_float(((unsigned int)b) << 16);
    bool bad = !(fabsf(v) < 1000.0f) || (v != 0.0f && fabsf(v) < 1e-15f);
    unsigned long long m = __ballot(bad);
    return (__popcll(m) >= 8) ? 1 : 0;
}

__device__ __forceinline__ const float* uniform_ptr(const float* p) {
    uint64_t v = (uint64_t)p;
    uint32_t lo = __builtin_amdgcn_readfirstlane((uint32_t)v);
    uint32_t hi = __builtin_amdgcn_readfirstlane((uint32_t)(v >> 32));
    return (const float*)(((uint64_t)hi << 32) | lo);
}

// ---------------- prep: W1 fp32, B-matrix fp16 fragment-packed, q=x@Wq ------
// Bpk flat index = ((nt*8 + ks)*64 + lane)*8 + j  (one dwordx4 per lane/frag)
//   kk = ks*32 + (lane>>4)*8 + j  -> c = kk>>4, jj = kk&15   (K = (c,j) = 256)
//   nn = nt*16 + (lane&15)        -> net = nn>>7, m = (nn>>3)&15, o = nn&7
__global__ __launch_bounds__(256) void prep_kernel(
    const void* __restrict__ x, const void* __restrict__ Wq,
    const void* __restrict__ Wk1, const void* __restrict__ Wk2,
    const void* __restrict__ Wv1, const void* __restrict__ Wv2,
    float* __restrict__ w1k, float* __restrict__ w1v,
    float* __restrict__ qbuf, float* __restrict__ zbuf,
    float* __restrict__ outacc, _Float16* __restrict__ Bpk, int N)
{
    const int f32 = detect_f32(x);
    int i = blockIdx.x * 256 + threadIdx.x;
    if (i < 160) { w1k[i] = ldf(Wk1, i, f32); w1v[i] = ldf(Wv1, i, f32); }
    if (i < 65536) {
        int j = i & 7, lane = (i >> 3) & 63, ks = (i >> 9) & 7, nt = i >> 12;
        int kk = ks * 32 + (lane >> 4) * 8 + j;
        int nn = nt * 16 + (lane & 15);
        int c = kk >> 4, jj = kk & 15;
        int net = nn >> 7, m = (nn >> 3) & 15, o = nn & 7;
        float v = ldf(net ? Wv2 : Wk2, m * 2048 + c * 128 + jj * 8 + o, f32);
        Bpk[i] = (_Float16)v;
    }
    if (i < N) zbuf[i] = 0.0f;
    if (i < N * 8) {
        outacc[i] = 0.0f;
        int n = i >> 3, o = i & 7;
        float acc = 0.0f;
        #pragma unroll
        for (int c = 0; c < CDIM; ++c)
            acc = fmaf(ldf(x, n * CDIM + c, f32), ldf(Wq, c * DKDIM + o, f32), acc);
        qbuf[i] = acc;
    }
}

// ---------------- edge kernel: geometry -> fp16 MFMA GEMM -> epilogue -------
// block = 256 thr = 4 waves = 64 edges. T = Y[64,256] @ B[256,256] via
// mfma_f32_16x16x32_f16 (wave w owns edge-rows 16w..16w+15, all 16 n-tiles).
// T lives in LDS (union-overlaid on xs/sh). Epilogue: k/v = h-contraction of
// T, logit, folded softmax (out += sqrt(ev)*v; finalize divides by sqrt(z)).
__global__ __launch_bounds__(256) void edge_kernel(
    const void* __restrict__ pos, const void* __restrict__ x,
    const int* __restrict__ esrc, const int* __restrict__ edst,
    const float* __restrict__ w1k, const float* __restrict__ w1v,
    const float* __restrict__ qbuf, const _Float16* __restrict__ Bpk,
    float* __restrict__ zbuf, float* __restrict__ outacc, int E)
{
    __shared__ union {
        struct { float xs[64][17]; float sh[64][20]; } g;  // geometry phase
        float T[64][ST];                                   // GEMM result phase
    } u;
    __shared__ float hm_lds[64][33];   // [e][m]: k-net m 0..15, v-net 16..31
    __shared__ float cut_lds[64];
    __shared__ float evs_lds[64];
    __shared__ float plgt[64][4];
    __shared__ int   d_lds[64];

    const int f32  = detect_f32(x);
    const int tid  = threadIdx.x;
    const int lane = tid & 63;
    const int w    = tid >> 6;        // wave index = geometry part = o-pair
    const int e_loc = lane;
    const int e = blockIdx.x * 64 + e_loc;
    const int eidx = (e < E) ? e : (E - 1);
    const int s = esrc[eidx], d = edst[eidx];

    // ---- geometry (per-edge work split across the 4 waves) ----
    float vx = ldf(pos, s * 3 + 0, f32) - ldf(pos, d * 3 + 0, f32);
    float vy = ldf(pos, s * 3 + 1, f32) - ldf(pos, d * 3 + 1, f32);
    float vz = ldf(pos, s * 3 + 2, f32) - ldf(pos, d * 3 + 2, f32);
    float r2 = vx * vx + vy * vy + vz * vz;
    float r  = sqrtf(r2 + 1e-18f);          // ref: emb/cutoff radius has +eps

    if (w == 0) {            // spherical harmonics + cutoff + dst
        float rsh = sqrtf(r2);              // ref: SH radius has no eps
        float inv = 1.0f / fmaxf(rsh, 1e-9f);
        float ux = vx * inv, uy = vy * inv, uz = vz * inv;
        const float s3   = 1.7320508075688772f;
        const float s5   = 2.23606797749979f;
        const float s15  = 3.872983346207417f;
        const float c358 = 2.091650066335189f;
        const float c218 = 1.6201851746019651f;
        const float s105 = 10.246950765959598f;
        const float s7h  = 1.3228756555322954f;
        float xx = ux * ux, yy = uy * uy, zz = uz * uz;
        float sh[16];
        sh[0] = 1.0f;
        sh[1] = s3 * ux; sh[2] = s3 * uy; sh[3] = s3 * uz;
        sh[4] = s15 * ux * uy;
        sh[5] = s15 * uy * uz;
        sh[6] = 0.5f * s5 * (3.0f * zz - 1.0f);
        sh[7] = s15 * ux * uz;
        sh[8] = 0.5f * s15 * (xx - yy);
        sh[9] = c358 * uy * (3.0f * xx - yy);
        sh[10] = s105 * ux * uy * uz;
        sh[11] = c218 * uy * (5.0f * zz - 1.0f);
        sh[12] = s7h * uz * (5.0f * zz - 3.0f);
        sh[13] = c218 * ux * (5.0f * zz - 1.0f);
        sh[14] = 0.5f * s105 * uz * (xx - yy);
        sh[15] = c358 * ux * (xx - 3.0f * yy);
        #pragma unroll
        for (int j = 0; j < 16; ++j) u.g.sh[e_loc][j] = sh[j];
        float tcut = 10.0f * (1.0f - r * (1.0f / 3.5f));
        cut_lds[e_loc] = (tcut > 0.0f) ? expf(-1.0f / tcut) : 0.0f;
        d_lds[e_loc] = d;
    } else if (w == 1) {     // xs gather
        #pragma unroll
        for (int c = 0; c < CDIM; ++c)
            u.g.xs[e_loc][c] = ldf(x, s * CDIM + c, f32);
    } else {                 // w=2: h_k, w=3: h_v
        const float* w1 = uniform_ptr((w == 2) ? w1k : w1v);
        const int off = (w == 2) ? 0 : 16;
        float emb[NBASIS];
        const float step = 3.5f / 11.0f;
        const float istep = 11.0f / 3.5f;
        const float coef = (float)(1.14136 * 7.38905609893065 * 3.1622776601683795);
        #pragma unroll
        for (int i = 0; i < NBASIS; ++i) {
            float uu = (r - step * (float)(i + 1)) * istep; uu *= uu;
            emb[i] = (uu < 1.0f) ? coef * expf(-1.0f / (1.0f - uu)) : 0.0f;
        }
        const float inv_s10 = 0.31622776601683794f;
        #pragma unroll
        for (int m = 0; m < 16; ++m) {
            float pre = 0.0f;
            #pragma unroll
            for (int nb = 0; nb < NBASIS; ++nb)
                pre = fmaf(emb[nb], w1[nb * 16 + m], pre);
            pre *= inv_s10;
            hm_lds[e_loc][off + m] = pre / (1.0f + expf(-pre));  // silu
        }
    }
    __syncthreads();

    // ---- A-fragment build: Y[e][kk] = xs_c * sh_jj, kk = c*16+jj ----
    // lane layout (A of 16x16x32): row = lane&15, k = (lane>>4)*8 + i
    const int q = lane >> 4;
    const int erow = w * 16 + (lane & 15);
    const int coff = q >> 1;
    const int jj0 = (q & 1) * 8;
    half8 af[8];
    #pragma unroll
    for (int ks = 0; ks < 8; ++ks) {
        float xsv = u.g.xs[erow][ks * 2 + coff];
        half8 a;
        #pragma unroll
        for (int j = 0; j < 8; ++j)
            a[j] = (_Float16)(xsv * u.g.sh[erow][jj0 + j]);
        af[ks] = a;
    }
    __syncthreads();   // xs/sh dead -> T may overlay

    // ---- MFMA: wave w computes T rows 16w..16w+15, all 256 cols ----
    #pragma unroll 1
    for (int nt = 0; nt < 16; nt += 2) {
        floatx4 acc0 = {0.f, 0.f, 0.f, 0.f};
        floatx4 acc1 = {0.f, 0.f, 0.f, 0.f};
        #pragma unroll
        for (int ks = 0; ks < 8; ++ks) {
            half8 b0 = ((const half8*)Bpk)[(nt * 8 + ks) * 64 + lane];
            half8 b1 = ((const half8*)Bpk)[((nt + 1) * 8 + ks) * 64 + lane];
            acc0 = __builtin_amdgcn_mfma_f32_16x16x32_f16(af[ks], b0, acc0, 0, 0, 0);
            acc1 = __builtin_amdgcn_mfma_f32_16x16x32_f16(af[ks], b1, acc1, 0, 0, 0);
        }
        // C/D layout: row = (lane>>4)*4 + r, col = lane&15
        const int col = lane & 15;
        #pragma unroll
        for (int rr = 0; rr < 4; ++rr) {
            int row = w * 16 + q * 4 + rr;
            u.T[row][nt * 16 + col] = acc0[rr];
            u.T[row][(nt + 1) * 16 + col] = acc1[rr];
        }
    }
    __syncthreads();

    // ---- epilogue A: thread (e_loc, w) handles o-pair (2w, 2w+1) ----
    const int o0 = w * 2, o1 = o0 + 1;
    float kk0 = 0.f, kk1 = 0.f, vv0 = 0.f, vv1 = 0.f;
    #pragma unroll
    for (int m = 0; m < 16; ++m) {
        float hk = hm_lds[e_loc][m], hv = hm_lds[e_loc][16 + m];
        kk0 = fmaf(hk, u.T[e_loc][m * 8 + o0], kk0);
        kk1 = fmaf(hk, u.T[e_loc][m * 8 + o1], kk1);
        vv0 = fmaf(hv, u.T[e_loc][128 + m * 8 + o0], vv0);
        vv1 = fmaf(hv, u.T[e_loc][128 + m * 8 + o1], vv1);
    }
    const float scale = 1.0f / 64.0f;  // 1/sqrt(16) fcnet * 1/sqrt(256) norm
    kk0 *= scale; kk1 *= scale; vv0 *= scale; vv1 *= scale;
    const int dd = d_lds[e_loc];
    plgt[e_loc][w] = fmaf(qbuf[(size_t)dd * 8 + o0], kk0,
                          qbuf[(size_t)dd * 8 + o1] * kk1);
    __syncthreads();

    if (tid < 64) {
        float logit = (plgt[tid][0] + plgt[tid][1] + plgt[tid][2] + plgt[tid][3])
                      * 0.35355339059327373f;             // 1/sqrt(8)
        float ev = cut_lds[tid] * expf(logit);            // matches ref path
        if (blockIdx.x * 64 + tid < E) atomicAdd(&zbuf[d_lds[tid]], ev);
        evs_lds[tid] = sqrtf(ev);
    }
    __syncthreads();

    if (e < E) {
        float wq = evs_lds[e_loc];
        atomicAdd(&outacc[(size_t)dd * 8 + o0], wq * vv0);
        atomicAdd(&outacc[(size_t)dd * 8 + o1], wq * vv1);
    }
}

// ---------------- finalize: out = outacc / sqrt(z), dtype-adaptive ----------
__global__ __launch_bounds__(256) void finalize_kernel(
    const float* __restrict__ outacc, const float* __restrict__ zbuf,
    void* __restrict__ out, const void* __restrict__ x, int n)
{
    const int f32 = detect_f32(x);
    int i = blockIdx.x * 256 + threadIdx.x;
    if (i < n) {
        float z = zbuf[i >> 3];
        z = (z == 0.0f) ? 1.0f : z;
        float val = outacc[i] / sqrtf(z);
        if (f32) ((float*)out)[i] = val;
        else ((__hip_bfloat16*)out)[i] = __float2bfloat16(val);
    }
}

extern "C" void kernel_launch(void* const* d_in, const int* in_sizes, int n_in,
                              void* d_out, int out_size, void* d_ws, size_t ws_size,
                              hipStream_t stream)
{
    const void* pos = d_in[0];
    const void* x   = d_in[1];
    const void* Wq  = d_in[2];
    const void* Wk1 = d_in[3];
    const void* Wk2 = d_in[4];
    const void* Wv1 = d_in[5];
    const void* Wv2 = d_in[6];
    const int* esrc = (const int*)d_in[7];
    const int* edst = (const int*)d_in[8];
    const int N = in_sizes[1] / CDIM;
    const int E = in_sizes[7];

    float* ws = (float*)d_ws;
    float* w1k    = ws;                          // 160
    float* w1v    = w1k + 160;                   // 160
    float* qbuf   = w1v + 160;                   // N*8
    float* zbuf   = qbuf + (size_t)N * 8;        // N
    float* outacc = zbuf + N;                    // N*8
    _Float16* Bpk = (_Float16*)(outacc + (size_t)N * 8);  // 65536 fp16

    int prep_threads = N * 8 > 65536 ? N * 8 : 65536;
    int prep_blocks = (prep_threads + 255) / 256;
    prep_kernel<<<prep_blocks, 256, 0, stream>>>(x, Wq, Wk1, Wk2, Wv1, Wv2,
                                                 w1k, w1v, qbuf, zbuf, outacc,
                                                 Bpk, N);

    int edge_blocks = (E + 63) / 64;
    edge_kernel<<<edge_blocks, 256, 0, stream>>>(pos, x, esrc, edst,
                                                 w1k, w1v, qbuf, Bpk,
                                                 zbuf, outacc, E);

    finalize_kernel<<<(N * 8 + 255) / 256, 256, 0, stream>>>(
        outacc, zbuf, d_out, x, N * 8);
}

// Round 8
// 113.581 us; speedup vs baseline: 4.6985x; 1.1331x over previous
//
#include <hip/hip_runtime.h>
#include <hip/hip_bf16.h>

#define NBASIS 10
#define CDIM 16
#define DKDIM 8
#define JDIM 16

typedef _Float16 half8 __attribute__((ext_vector_type(8)));
typedef float floatx4 __attribute__((ext_vector_type(4)));

// adaptive load: f32 flag (wave-uniform) selects fp32 or bf16 interpretation
__device__ __forceinline__ float ldf(const void* p, int i, int f32) {
    if (f32) return ((const float*)p)[i];
    return __bfloat162float(((const __hip_bfloat16*)p)[i]);
}

// per-wave input-dtype detect (round-2 notes): fp32 data read as bf16 shows
// implausible magnitudes in ~half the ushorts; bf16 N(0,1) shows none.
__device__ __forceinline__ int detect_f32(const void* x) {
    unsigned short b = ((const unsigned short*)x)[threadIdx.x & 63];
    float v = __uint_as_float(((unsigned int)b) << 16);
    bool bad = !(fabsf(v) < 1000.0f) || (v != 0.0f && fabsf(v) < 1e-15f);
    unsigned long long m = __ballot(bad);
    return (__popcll(m) >= 8) ? 1 : 0;
}

__device__ __forceinline__ const float* uniform_ptr(const float* p) {
    uint64_t v = (uint64_t)p;
    uint32_t lo = __builtin_amdgcn_readfirstlane((uint32_t)v);
    uint32_t hi = __builtin_amdgcn_readfirstlane((uint32_t)(v >> 32));
    return (const float*)(((uint64_t)hi << 32) | lo);
}

// ---------------- prep: W1 fp32, B-matrix fp16 fragment-packed, q=x@Wq ------
// Bpk flat index = ((nt*8 + ks)*64 + lane)*8 + j  (one dwordx4 per lane/frag)
//   kk = ks*32 + (lane>>4)*8 + j  -> c = kk>>4, jj = kk&15   (K = (c,j) = 256)
//   nn = nt*16 + (lane&15)        -> net = nn>>7, m = (nn>>3)&15, o = nn&7
__global__ __launch_bounds__(256) void prep_kernel(
    const void* __restrict__ x, const void* __restrict__ Wq,
    const void* __restrict__ Wk1, const void* __restrict__ Wk2,
    const void* __restrict__ Wv1, const void* __restrict__ Wv2,
    float* __restrict__ w1k, float* __restrict__ w1v,
    float* __restrict__ qbuf, float* __restrict__ zbuf,
    float* __restrict__ outacc, _Float16* __restrict__ Bpk, int N)
{
    const int f32 = detect_f32(x);
    int i = blockIdx.x * 256 + threadIdx.x;
    if (i < 160) { w1k[i] = ldf(Wk1, i, f32); w1v[i] = ldf(Wv1, i, f32); }
    if (i < 65536) {
        int j = i & 7, lane = (i >> 3) & 63, ks = (i >> 9) & 7, nt = i >> 12;
        int kk = ks * 32 + (lane >> 4) * 8 + j;
        int nn = nt * 16 + (lane & 15);
        int c = kk >> 4, jj = kk & 15;
        int net = nn >> 7, m = (nn >> 3) & 15, o = nn & 7;
        float v = ldf(net ? Wv2 : Wk2, m * 2048 + c * 128 + jj * 8 + o, f32);
        Bpk[i] = (_Float16)v;
    }
    if (i < N) zbuf[i] = 0.0f;
    if (i < N * 8) {
        outacc[i] = 0.0f;
        int n = i >> 3, o = i & 7;
        float acc = 0.0f;
        #pragma unroll
        for (int c = 0; c < CDIM; ++c)
            acc = fmaf(ldf(x, n * CDIM + c, f32), ldf(Wq, c * DKDIM + o, f32), acc);
        qbuf[i] = acc;
    }
}

// ---------------- edge kernel: geometry -> MFMA GEMM -> in-register epilogue
// block = 256 thr = 4 waves = 64 edges. Wave w owns nt-quarter {4w..4w+3} for
// ALL 64 edges (row-tile pairs share each B fragment). D never hits LDS:
// per-lane h-contraction over nt (m = (2nt + col>>3)&15, o = col&7) then
// shfl_xor(8) merges m-halves; per-net partials combine via small LDS bufs.
__global__ __launch_bounds__(256) void edge_kernel(
    const void* __restrict__ pos, const void* __restrict__ x,
    const int* __restrict__ esrc, const int* __restrict__ edst,
    const float* __restrict__ w1k, const float* __restrict__ w1v,
    const float* __restrict__ qbuf, const _Float16* __restrict__ Bpk,
    float* __restrict__ zbuf, float* __restrict__ outacc, int E)
{
    __shared__ union {
        struct { float xs[64][17]; float sh[64][17]; } g;   // geometry phase
        _Float16 A[16384];            // [r][ks][lane][8] fp16 frags, 32 KB
        struct { float pk[2][64][9]; float pv[2][64][9]; } p; // partial k/v
    } u;
    __shared__ _Float16 hm_lds[64][34];  // [e][net*16 + m]
    __shared__ float cut_lds[64];
    __shared__ float evs_lds[64];
    __shared__ int   d_lds[64];

    const int f32  = detect_f32(x);
    const int tid  = threadIdx.x;
    const int lane = tid & 63;
    const int w    = tid >> 6;
    const int q    = lane >> 4;
    const int e0   = blockIdx.x * 64;
    const int e_g  = e0 + lane;
    const int eidx = (e_g < E) ? e_g : (E - 1);
    const int s = esrc[eidx], d = edst[eidx];

    // ---- geometry (per-edge work split across the 4 waves) ----
    float vx = ldf(pos, s * 3 + 0, f32) - ldf(pos, d * 3 + 0, f32);
    float vy = ldf(pos, s * 3 + 1, f32) - ldf(pos, d * 3 + 1, f32);
    float vz = ldf(pos, s * 3 + 2, f32) - ldf(pos, d * 3 + 2, f32);
    float r2 = vx * vx + vy * vy + vz * vz;
    float r  = sqrtf(r2 + 1e-18f);          // ref: emb/cutoff radius has +eps

    if (w == 0) {            // spherical harmonics + cutoff + dst
        float rsh = sqrtf(r2);              // ref: SH radius has no eps
        float inv = 1.0f / fmaxf(rsh, 1e-9f);
        float ux = vx * inv, uy = vy * inv, uz = vz * inv;
        const float s3   = 1.7320508075688772f;
        const float s5   = 2.23606797749979f;
        const float s15  = 3.872983346207417f;
        const float c358 = 2.091650066335189f;
        const float c218 = 1.6201851746019651f;
        const float s105 = 10.246950765959598f;
        const float s7h  = 1.3228756555322954f;
        float xx = ux * ux, yy = uy * uy, zz = uz * uz;
        float sh[16];
        sh[0] = 1.0f;
        sh[1] = s3 * ux; sh[2] = s3 * uy; sh[3] = s3 * uz;
        sh[4] = s15 * ux * uy;
        sh[5] = s15 * uy * uz;
        sh[6] = 0.5f * s5 * (3.0f * zz - 1.0f);
        sh[7] = s15 * ux * uz;
        sh[8] = 0.5f * s15 * (xx - yy);
        sh[9] = c358 * uy * (3.0f * xx - yy);
        sh[10] = s105 * ux * uy * uz;
        sh[11] = c218 * uy * (5.0f * zz - 1.0f);
        sh[12] = s7h * uz * (5.0f * zz - 3.0f);
        sh[13] = c218 * ux * (5.0f * zz - 1.0f);
        sh[14] = 0.5f * s105 * uz * (xx - yy);
        sh[15] = c358 * ux * (xx - 3.0f * yy);
        #pragma unroll
        for (int j = 0; j < 16; ++j) u.g.sh[lane][j] = sh[j];
        float tcut = 10.0f * (1.0f - r * (1.0f / 3.5f));
        cut_lds[lane] = (tcut > 0.0f) ? expf(-1.0f / tcut) : 0.0f;
        d_lds[lane] = d;
    } else if (w == 1) {     // xs gather
        #pragma unroll
        for (int c = 0; c < CDIM; ++c)
            u.g.xs[lane][c] = ldf(x, s * CDIM + c, f32);
    } else {                 // w=2: h_k, w=3: h_v (fp16 into hm_lds)
        const float* w1 = uniform_ptr((w == 2) ? w1k : w1v);
        const int off = (w == 2) ? 0 : 16;
        float emb[NBASIS];
        const float step = 3.5f / 11.0f;
        const float istep = 11.0f / 3.5f;
        const float coef = (float)(1.14136 * 7.38905609893065 * 3.1622776601683795);
        #pragma unroll
        for (int i = 0; i < NBASIS; ++i) {
            float uu = (r - step * (float)(i + 1)) * istep; uu *= uu;
            emb[i] = (uu < 1.0f) ? coef * expf(-1.0f / (1.0f - uu)) : 0.0f;
        }
        const float inv_s10 = 0.31622776601683794f;
        #pragma unroll
        for (int m = 0; m < 16; ++m) {
            float pre = 0.0f;
            #pragma unroll
            for (int nb = 0; nb < NBASIS; ++nb)
                pre = fmaf(emb[nb], w1[nb * 16 + m], pre);
            pre *= inv_s10;
            hm_lds[lane][off + m] = (_Float16)(pre / (1.0f + expf(-pre)));
        }
    }
    __syncthreads();

    // ---- A-frag build in regs (wave w -> row-tile r=w) ----
    half8 af[8];
    {
        const int erow = w * 16 + (lane & 15);
        const int coff = q >> 1, jj0 = (q & 1) * 8;
        #pragma unroll
        for (int ks = 0; ks < 8; ++ks) {
            float xsv = u.g.xs[erow][ks * 2 + coff];
            half8 a;
            #pragma unroll
            for (int j = 0; j < 8; ++j)
                a[j] = (_Float16)(xsv * u.g.sh[erow][jj0 + j]);
            af[ks] = a;
        }
    }
    __syncthreads();          // all g reads done -> overlay A
    {
        half8* Af = (half8*)u.A;
        #pragma unroll
        for (int ks = 0; ks < 8; ++ks)
            Af[(w * 8 + ks) * 64 + lane] = af[ks];
    }
    __syncthreads();

    // ---- GEMM over row-tile pairs + in-register h-contraction ----
    float part[16];           // [r][rr] partial k or v for edge r*16+q*4+rr
    #pragma unroll
    for (int i = 0; i < 16; ++i) part[i] = 0.0f;
    const int b3   = (lane >> 3) & 1;   // col>>3: which m-half this lane holds
    const int moff = (w >> 1) * 16;     // net offset into hm_lds (k=0, v=16)
    const half8* Af = (const half8*)u.A;
    const half8* Bf = (const half8*)Bpk;

    #pragma unroll
    for (int rp = 0; rp < 2; ++rp) {
        half8 a0[8], a1[8];
        #pragma unroll
        for (int ks = 0; ks < 8; ++ks) {
            a0[ks] = Af[((2 * rp)     * 8 + ks) * 64 + lane];
            a1[ks] = Af[((2 * rp + 1) * 8 + ks) * 64 + lane];
        }
        floatx4 acc0[4], acc1[4];
        #pragma unroll
        for (int l = 0; l < 4; ++l) {
            acc0[l] = (floatx4){0.f, 0.f, 0.f, 0.f};
            acc1[l] = (floatx4){0.f, 0.f, 0.f, 0.f};
        }
        #pragma unroll
        for (int l = 0; l < 4; ++l) {
            const int nt = 4 * w + l;
            #pragma unroll
            for (int ks = 0; ks < 8; ++ks) {
                half8 b = Bf[(nt * 8 + ks) * 64 + lane];
                acc0[l] = __builtin_amdgcn_mfma_f32_16x16x32_f16(a0[ks], b, acc0[l], 0, 0, 0);
                acc1[l] = __builtin_amdgcn_mfma_f32_16x16x32_f16(a1[ks], b, acc1[l], 0, 0, 0);
            }
        }
        #pragma unroll
        for (int l = 0; l < 4; ++l) {
            const int m = ((4 * w + l) * 2 + b3) & 15;
            #pragma unroll
            for (int rr = 0; rr < 4; ++rr) {
                const int er = q * 4 + rr;
                part[(2 * rp) * 4 + rr] +=
                    (float)hm_lds[(2 * rp) * 16 + er][moff + m] * acc0[l][rr];
                part[(2 * rp + 1) * 4 + rr] +=
                    (float)hm_lds[(2 * rp + 1) * 16 + er][moff + m] * acc1[l][rr];
            }
        }
    }
    // merge the two m-halves (lanes col and col^8 hold same (e,o))
    #pragma unroll
    for (int i = 0; i < 16; ++i) part[i] += __shfl_xor(part[i], 8, 64);

    __syncthreads();          // A reads done -> overlay partial buffers
    if (b3 == 0) {
        const int o = lane & 7;
        #pragma unroll
        for (int i = 0; i < 16; ++i) {
            const int e = (i >> 2) * 16 + q * 4 + (i & 3);
            if (w < 2) u.p.pk[w][e][o] = part[i];
            else       u.p.pv[w - 2][e][o] = part[i];
        }
    }
    __syncthreads();

    // ---- softmax: logit -> ev -> atomic z (one thread per edge) ----
    if (tid < 64) {
        const int dd = d_lds[tid];
        float logit = 0.0f;
        #pragma unroll
        for (int o = 0; o < 8; ++o) {
            float kv = u.p.pk[0][tid][o] + u.p.pk[1][tid][o];
            logit = fmaf(qbuf[(size_t)dd * 8 + o], kv, logit);
        }
        // scale: 1/64 (fcnet+norm) * 1/sqrt(8) (dk)
        logit *= (1.0f / 64.0f) * 0.35355339059327373f;
        float ev = cut_lds[tid] * expf(logit);   // unstabilized, matches ref
        if (e0 + tid < E) atomicAdd(&zbuf[dd], ev);
        evs_lds[tid] = sqrtf(ev);
    }
    __syncthreads();

    // ---- out += sqrt(ev) * v (folded softmax; finalize divides by sqrt(z))
    {
        const int el = tid & 63, op = tid >> 6;
        if (e0 + el < E) {
            const int dd = d_lds[el];
            const float wq = evs_lds[el] * (1.0f / 64.0f);
            float v0 = u.p.pv[0][el][2 * op]     + u.p.pv[1][el][2 * op];
            float v1 = u.p.pv[0][el][2 * op + 1] + u.p.pv[1][el][2 * op + 1];
            atomicAdd(&outacc[(size_t)dd * 8 + 2 * op],     wq * v0);
            atomicAdd(&outacc[(size_t)dd * 8 + 2 * op + 1], wq * v1);
        }
    }
}

// ---------------- finalize: out = outacc / sqrt(z), dtype-adaptive ----------
__global__ __launch_bounds__(256) void finalize_kernel(
    const float* __restrict__ outacc, const float* __restrict__ zbuf,
    void* __restrict__ out, const void* __restrict__ x, int n)
{
    const int f32 = detect_f32(x);
    int i = blockIdx.x * 256 + threadIdx.x;
    if (i < n) {
        float z = zbuf[i >> 3];
        z = (z == 0.0f) ? 1.0f : z;
        float val = outacc[i] / sqrtf(z);
        if (f32) ((float*)out)[i] = val;
        else ((__hip_bfloat16*)out)[i] = __float2bfloat16(val);
    }
}

extern "C" void kernel_launch(void* const* d_in, const int* in_sizes, int n_in,
                              void* d_out, int out_size, void* d_ws, size_t ws_size,
                              hipStream_t stream)
{
    const void* pos = d_in[0];
    const void* x   = d_in[1];
    const void* Wq  = d_in[2];
    const void* Wk1 = d_in[3];
    const void* Wk2 = d_in[4];
    const void* Wv1 = d_in[5];
    const void* Wv2 = d_in[6];
    const int* esrc = (const int*)d_in[7];
    const int* edst = (const int*)d_in[8];
    const int N = in_sizes[1] / CDIM;
    const int E = in_sizes[7];

    float* ws = (float*)d_ws;
    float* w1k    = ws;                          // 160
    float* w1v    = w1k + 160;                   // 160
    float* qbuf   = w1v + 160;                   // N*8
    float* zbuf   = qbuf + (size_t)N * 8;        // N
    float* outacc = zbuf + N;                    // N*8
    _Float16* Bpk = (_Float16*)(outacc + (size_t)N * 8);  // 65536 fp16

    int prep_threads = N * 8 > 65536 ? N * 8 : 65536;
    int prep_blocks = (prep_threads + 255) / 256;
    prep_kernel<<<prep_blocks, 256, 0, stream>>>(x, Wq, Wk1, Wk2, Wv1, Wv2,
                                                 w1k, w1v, qbuf, zbuf, outacc,
                                                 Bpk, N);

    int edge_blocks = (E + 63) / 64;
    edge_kernel<<<edge_blocks, 256, 0, stream>>>(pos, x, esrc, edst,
                                                 w1k, w1v, qbuf, Bpk,
                                                 zbuf, outacc, E);

    finalize_kernel<<<(N * 8 + 255) / 256, 256, 0, stream>>>(
        outacc, zbuf, d_out, x, N * 8);
}